// Round 3
// baseline (346.585 us; speedup 1.0000x reference)
//
#include <hip/hip_runtime.h>
#include <cstdint>
#include <cstddef>

// Problem constants
constexpr int DD = 1024;        // D
constexpr int TT = 4096;        // T
constexpr int BB = 4;           // B
constexpr int MM = BB * TT;     // 16384 rows

typedef __bf16 bf16x8 __attribute__((ext_vector_type(8)));
typedef float  f32x4  __attribute__((ext_vector_type(4)));

__device__ __forceinline__ unsigned short f2bf(float f) {
  union { float f; uint32_t u; } c; c.f = f;
  uint32_t r = (c.u + 0x7FFFu + ((c.u >> 16) & 1u)) >> 16;
  return (unsigned short)r;
}

__device__ __forceinline__ float fast_rcp(float x) {
  return __builtin_amdgcn_rcpf(x);
}

// async global->LDS 16B per lane; lds_dst must be wave-uniform (HW adds lane*16)
__device__ __forceinline__ void async_ld16(const unsigned short* g, unsigned short* lds_dst) {
  __builtin_amdgcn_global_load_lds(
      (const __attribute__((address_space(1))) void*)g,
      (__attribute__((address_space(3))) void*)lds_dst,
      16, 0, 0);
}

#define VWAIT(n) asm volatile("s_waitcnt vmcnt(" #n ")" ::: "memory")
#define LWAIT(n) asm volatile("s_waitcnt lgkmcnt(" #n ")" ::: "memory")
#define SB()     __builtin_amdgcn_sched_barrier(0)

// R1-verified st_16x32-style swizzle (measured 0 bank conflicts): XOR byte
// bit-9 into bit-5 within each 1024B plane (16 rows of 64B). Involution.
__device__ __forceinline__ int swzb(int b) { return b ^ (((b >> 9) & 1) << 5); }

// ---------------------------------------------------------------------------
// Merged prep: blocks [0,1024) fold time-mix into weights (wave per row) and
// accumulate bias dots; blocks [1024, 1024+16384) convert x to bf16 and emit
// x[:, T-1, :].
__global__ void prep_all(const float* __restrict__ Wk, const float* __restrict__ Wv,
                         const float* __restrict__ Wr, const float* __restrict__ Wo,
                         const float* __restrict__ tmk, const float* __restrict__ tmv,
                         const float* __restrict__ tmr,
                         const float* __restrict__ last_x,
                         const float4* __restrict__ x,
                         unsigned short* __restrict__ wz,   // [3][1024][1024] bf16
                         unsigned short* __restrict__ wo,   // [1024][1024] bf16
                         float* __restrict__ bias,          // [3][1024]
                         ushort4* __restrict__ xb,          // [16384][1024] bf16
                         float4* __restrict__ out_xlast) {
  if (blockIdx.x < 1024) {
    int w = (blockIdx.x * 256 + threadIdx.x) >> 6;   // 0..4095
    int lane = threadIdx.x & 63;
    int z = w >> 10;           // 0..3
    int e = w & (DD - 1);
    const float* W  = (z == 0) ? Wk  : (z == 1) ? Wv  : (z == 2) ? Wr : Wo;
    const float* tm = (z == 0) ? tmk : (z == 1) ? tmv : tmr;
    unsigned short* dst = (z < 3) ? (wz + (size_t)z * DD * DD + (size_t)e * DD)
                                  : (wo + (size_t)e * DD);
    float s = 0.f;
#pragma unroll
    for (int j = 0; j < 4; ++j) {
      int d = j * 256 + lane * 4;
      float4 wv4 = *(const float4*)(W + (size_t)e * DD + d);
      if (z < 3) {
        float4 t4 = *(const float4*)(tm + d);
        float4 l4 = *(const float4*)(last_x + d);
        s += l4.x * (1.f - t4.x) * wv4.x + l4.y * (1.f - t4.y) * wv4.y +
             l4.z * (1.f - t4.z) * wv4.z + l4.w * (1.f - t4.w) * wv4.w;
        wv4.x *= t4.x; wv4.y *= t4.y; wv4.z *= t4.z; wv4.w *= t4.w;
      }
      ushort4 o;
      o.x = f2bf(wv4.x); o.y = f2bf(wv4.y); o.z = f2bf(wv4.z); o.w = f2bf(wv4.w);
      *(ushort4*)(dst + d) = o;
    }
    if (z < 3) {
      for (int off = 32; off; off >>= 1) s += __shfl_down(s, off, 64);
      if (lane == 0) bias[z * DD + e] = s;
    }
  } else {
    int i = (blockIdx.x - 1024) * 256 + threadIdx.x;  // < MM*DD/4
    float4 v = x[i];
    ushort4 o;
    o.x = f2bf(v.x); o.y = f2bf(v.y); o.z = f2bf(v.z); o.w = f2bf(v.w);
    xb[i] = o;
    int m = i >> 8;                                    // 256 float4 per row
    if ((m & (TT - 1)) == (TT - 1)) {
      int b = m >> 12;
      out_xlast[b * 256 + (i & 255)] = v;
    }
  }
}

// ---------------------------------------------------------------------------
// Fused GEMM1 + WKV. 256-row tile, 64-col n-zone, 3 z-matrices.
// 4-slot ring of K-half steps (BK=32), prefetch distance 3, counted per-role
// vmcnt (A-waves 8 / B-waves 6) -> never a full drain in the main loop.
// R1-verified swizzle (0 conflicts). Fine interleave via counted lgkmcnt:
// all 10 ds_reads issued up front in pinned groups, MFMA clusters of 8
// between lgkmcnt(4)/(2)/(0) so z1/z2 read-drain overlaps z0/z1 MFMA.
// ONE barrier per step (after the counted vmcnt): safe because every wave's
// slot-s reads are lgkm-drained before the end-of-step barrier, so staging
// into slot s during step s+1 cannot race.
__global__ __launch_bounds__(512, 2) void gemm_kvr(
    const unsigned short* __restrict__ A,     // [16384][1024] bf16
    const unsigned short* __restrict__ Wz,    // [3][1024][1024] bf16
    const float* __restrict__ bias,           // [3][1024]
    const float* __restrict__ time_first, const float* __restrict__ time_decay,
    const float* __restrict__ last_num, const float* __restrict__ last_den,
    unsigned short* __restrict__ rwkv,        // [16384][1024] bf16
    float* __restrict__ out_num, float* __restrict__ out_den) {
  // Ring of 4 K-half slots: A 256x32 (16KiB), B 192x32 (12KiB) -> 112 KiB
  __shared__ __align__(1024) unsigned short rA[4][256 * 32];
  __shared__ __align__(1024) unsigned short rB[4][192 * 32];
  const int tid  = threadIdx.x;
  const int lane = tid & 63;
  const int wave = tid >> 6;

  // XCD-aware remap. Grid: 16 x 64 = 1024 blocks; 8 m-stripes x 16 n-zones per XCD.
  const int id  = blockIdx.y * gridDim.x + blockIdx.x;   // 0..1023
  const int xcd = id & 7;
  const int s_  = id >> 3;                               // 0..127
  const int m0 = (xcd * 8 + (s_ >> 4)) * 256;            // m-stripe (256 rows)
  const int n0 = (s_ & 15) * 64;                         // zone-local col base

  const int wm = (wave >> 1) * 64;   // 4 m-groups of 64
  const int wn = (wave & 1) * 32;    // 2 n-groups of 32
  const int fr = lane & 15;
  const int fq = lane >> 4;

  // Fragment ds_read byte offsets (slot-relative, R1-verified swizzle).
  int phA[4], phB[3][2];
#pragma unroll
  for (int m = 0; m < 4; ++m)
    phA[m] = swzb((wm + m * 16 + fr) * 64 + fq * 16);
#pragma unroll
  for (int z = 0; z < 3; ++z)
#pragma unroll
    for (int n = 0; n < 2; ++n)
      phB[z][n] = swzb((z * 64 + wn + n * 16 + fr) * 64 + fq * 16);

  // Staging: waves 0-3 stage A (4 x 1KiB issues/step), waves 4-7 stage B (3).
  // Linear LDS dest (idx*1024 + lane*16); logical byte recovered via the same
  // swizzle (involution) -> per-lane inverse-swizzled global source.
  size_t srcOff[4];
  int dstOff[4];
  if (wave < 4) {
#pragma unroll
    for (int j = 0; j < 4; ++j) {
      int idx = wave * 4 + j;                 // 0..15
      int pb = idx * 1024 + lane * 16;        // physical byte this lane fills
      int lq = swzb(pb);                      // logical byte
      int r = lq >> 6, cb = lq & 63;          // row 0..255, 16B-aligned col byte
      srcOff[j] = (size_t)(m0 + r) * DD + cb / 2;
      dstOff[j] = idx * 1024;
    }
  } else {
#pragma unroll
    for (int j = 0; j < 3; ++j) {
      int idx = (wave - 4) * 3 + j;           // 0..11
      int pb = idx * 1024 + lane * 16;
      int lq = swzb(pb);
      int r = lq >> 6, cb = lq & 63;          // row 0..191
      int z = r >> 6, zr = r & 63;
      srcOff[j] = (size_t)z * DD * DD + (size_t)(n0 + zr) * DD + cb / 2;
      dstOff[j] = idx * 1024;
    }
  }

  auto stage = [&](int slot, int stp) {
    const int ke = stp * 32;
    if (wave < 4) {
#pragma unroll
      for (int j = 0; j < 4; ++j)
        async_ld16(A + srcOff[j] + ke, (unsigned short*)((char*)rA[slot] + dstOff[j]));
    } else {
#pragma unroll
      for (int j = 0; j < 3; ++j)
        async_ld16(Wz + srcOff[j] + ke, (unsigned short*)((char*)rB[slot] + dstOff[j]));
    }
  };

  f32x4 acc[3][4][2] = {};

  // Prologue: fill slots 0,1,2; wait for slot 0 (2 stage-groups in flight).
  stage(0, 0);
  stage(1, 1);
  stage(2, 2);
  if (wave < 4) VWAIT(8); else VWAIT(6);
  SB();
  __builtin_amdgcn_s_barrier();

#pragma unroll 1
  for (int s = 0; s < 32; ++s) {
    const int slot = s & 3;
    // Earliest possible issue of the prefetch (slot s+3 == s-1 mod 4; all
    // waves' reads of that slot were lgkm-drained before the last barrier).
    if (s < 29) stage((s + 3) & 3, s + 3);

    // Group 1: A frags + B z0 (6 reads). Order pinned vs later groups so the
    // counted lgkmcnt refers to the right reads (DS completes in-order).
    bf16x8 af[4];
#pragma unroll
    for (int m = 0; m < 4; ++m)
      af[m] = *(const bf16x8*)((const char*)rA[slot] + phA[m]);
    bf16x8 b0[2];
#pragma unroll
    for (int n = 0; n < 2; ++n)
      b0[n] = *(const bf16x8*)((const char*)rB[slot] + phB[0][n]);
    SB();
    // Group 2: B z1 (2 reads)
    bf16x8 b1[2];
#pragma unroll
    for (int n = 0; n < 2; ++n)
      b1[n] = *(const bf16x8*)((const char*)rB[slot] + phB[1][n]);
    SB();
    // Group 3: B z2 (2 reads)
    bf16x8 b2[2];
#pragma unroll
    for (int n = 0; n < 2; ++n)
      b2[n] = *(const bf16x8*)((const char*)rB[slot] + phB[2][n]);
    SB();

    LWAIT(4); SB();          // groups 1 done (6 oldest of 10)
    __builtin_amdgcn_s_setprio(1);
#pragma unroll
    for (int m = 0; m < 4; ++m)
#pragma unroll
      for (int n = 0; n < 2; ++n)
        acc[0][m][n] = __builtin_amdgcn_mfma_f32_16x16x32_bf16(
            af[m], b0[n], acc[0][m][n], 0, 0, 0);
    __builtin_amdgcn_s_setprio(0);

    LWAIT(2); SB();          // group 2 done
    __builtin_amdgcn_s_setprio(1);
#pragma unroll
    for (int m = 0; m < 4; ++m)
#pragma unroll
      for (int n = 0; n < 2; ++n)
        acc[1][m][n] = __builtin_amdgcn_mfma_f32_16x16x32_bf16(
            af[m], b1[n], acc[1][m][n], 0, 0, 0);
    __builtin_amdgcn_s_setprio(0);

    LWAIT(0); SB();          // all reads done
    __builtin_amdgcn_s_setprio(1);
#pragma unroll
    for (int m = 0; m < 4; ++m)
#pragma unroll
      for (int n = 0; n < 2; ++n)
        acc[2][m][n] = __builtin_amdgcn_mfma_f32_16x16x32_bf16(
            af[m], b2[n], acc[2][m][n], 0, 0, 0);
    __builtin_amdgcn_s_setprio(0);

    if (s < 31) {
      // Counted publish of slot s+1; 2 (or fewer, in tail) stage-groups
      // remain in flight. Single barrier per step.
      if (s < 29)       { if (wave < 4) VWAIT(8); else VWAIT(6); }
      else if (s == 29) { if (wave < 4) VWAIT(4); else VWAIT(3); }
      else              { VWAIT(0); }
      __builtin_amdgcn_s_barrier();
    }
  }

  // Epilogue: WKV in-register. C/D layout: col = lane&15, row = (lane>>4)*4 + reg.
  const int crow = fq * 4;
  const int ccol = fr;
#pragma unroll
  for (int ni = 0; ni < 2; ++ni) {
    int gnz = n0 + wn + ni * 16 + ccol;   // channel d
    float bk = bias[gnz], bv = bias[DD + gnz], br = bias[2 * DD + gnz];
    float tf = time_first[gnz];
    float ln = last_num[gnz], ld = last_den[gnz];
    float dec = __expf(-__expf(time_decay[gnz]));   // hoisted
#pragma unroll
    for (int mi = 0; mi < 4; ++mi) {
#pragma unroll
      for (int r = 0; r < 4; ++r) {
        int gm = m0 + wm + mi * 16 + crow + r;
        float kk = acc[0][mi][ni][r] + bk;
        float vv = acc[1][mi][ni][r] + bv;
        float rr = acc[2][mi][ni][r] + br;
        float efk = __expf(tf + kk);
        float wkv = (ln + efk * vv) * fast_rcp(ld + efk);
        float sr  = fast_rcp(1.0f + __expf(-rr));
        rwkv[(size_t)gm * DD + gnz] = f2bf(sr * wkv);
        if ((gm & (TT - 1)) == (TT - 1)) {
          int b = gm >> 12;
          float ek = __expf(kk);
          out_num[b * DD + gnz] = dec * ln + ek * vv;
          out_den[b * DD + gnz] = dec * ld + ek;
        }
      }
    }
  }
}

// ---------------------------------------------------------------------------
// GEMM2: C[M,N] = A[M,K] @ B[N,K]^T, fp32 out. Two-panel BK=64 (R3 structure)
// + XCD-locality swizzle.
__global__ void gemm_bt128(const unsigned short* __restrict__ A,
                           const unsigned short* __restrict__ Bw,
                           float* __restrict__ Cf,
                           int M, int N, int K) {
  __shared__ unsigned short lA[2][128 * 32];
  __shared__ unsigned short lB[2][128 * 32];
  const int tid  = threadIdx.x;
  const int lane = tid & 63;
  const int wave = tid >> 6;

  // XCD-aware remap: m-stripes partitioned across XCDs, n fastest.
  const int nBlocks = N >> 7;
  const int mBlocks = M >> 7;
  const int id  = blockIdx.y * gridDim.x + blockIdx.x;
  const int xcd = id & 7;
  const int s   = id >> 3;
  const int mPer = mBlocks >> 3;           // m-stripes per XCD (M=16384 -> 16)
  const int m0 = (xcd * mPer + s / nBlocks) * 128;
  const int n0 = (s % nBlocks) * 128;

  const int wm = (wave >> 1) * 64;
  const int wn = (wave & 1) * 64;

  f32x4 acc[4][4] = {};
  const int fr_row = lane & 15;
  const int fr_kb  = (lane >> 4) * 16;
  const int scol = (tid & 3) * 8;

  for (int k0 = 0; k0 < K; k0 += 64) {
    __syncthreads();
#pragma unroll
    for (int h = 0; h < 2; ++h) {
      int kk = k0 + h * 32;
#pragma unroll
      for (int it = 0; it < 2; ++it) {
        int cc  = it * 256 + tid;
        int row = cc >> 2;
        async_ld16(A + (size_t)(m0 + row) * K + (kk + scol),
                   lA[h] + (size_t)(it * 256 + wave * 64) * 8);
      }
#pragma unroll
      for (int it = 0; it < 2; ++it) {
        int cc  = it * 256 + tid;
        int row = cc >> 2;
        async_ld16(Bw + (size_t)(n0 + row) * K + (kk + scol),
                   lB[h] + (size_t)(it * 256 + wave * 64) * 8);
      }
    }
    __syncthreads();

#pragma unroll
    for (int h = 0; h < 2; ++h) {
      bf16x8 af[4], bfr[4];
#pragma unroll
      for (int i = 0; i < 4; ++i) {
        af[i]  = *(const bf16x8*)((const char*)lA[h] + ((wm + i * 16 + fr_row) * 64 + fr_kb));
        bfr[i] = *(const bf16x8*)((const char*)lB[h] + ((wn + i * 16 + fr_row) * 64 + fr_kb));
      }
#pragma unroll
      for (int mi = 0; mi < 4; ++mi)
#pragma unroll
        for (int ni = 0; ni < 4; ++ni)
          acc[mi][ni] = __builtin_amdgcn_mfma_f32_16x16x32_bf16(af[mi], bfr[ni], acc[mi][ni], 0, 0, 0);
    }
  }

  const int crow = (lane >> 4) * 4;
  const int ccol = lane & 15;
#pragma unroll
  for (int mi = 0; mi < 4; ++mi) {
#pragma unroll
    for (int ni = 0; ni < 4; ++ni) {
      int gn = n0 + wn + ni * 16 + ccol;
#pragma unroll
      for (int r = 0; r < 4; ++r) {
        int gm = m0 + wm + mi * 16 + crow + r;
        Cf[(size_t)gm * N + gn] = acc[mi][ni][r];
      }
    }
  }
}

// ---------------------------------------------------------------------------
extern "C" void kernel_launch(void* const* d_in, const int* in_sizes, int n_in,
                              void* d_out, int out_size, void* d_ws, size_t ws_size,
                              hipStream_t stream) {
  const float* x          = (const float*)d_in[0];
  const float* last_x     = (const float*)d_in[1];
  const float* last_num   = (const float*)d_in[2];
  const float* last_den   = (const float*)d_in[3];
  const float* time_decay = (const float*)d_in[4];
  const float* time_first = (const float*)d_in[5];
  const float* tmk        = (const float*)d_in[6];
  const float* tmv        = (const float*)d_in[7];
  const float* tmr        = (const float*)d_in[8];
  const float* Wk         = (const float*)d_in[9];
  const float* Wv         = (const float*)d_in[10];
  const float* Wr         = (const float*)d_in[11];
  const float* Wo         = (const float*)d_in[12];

  float* out       = (float*)d_out;                  // [MM][DD]
  float* out_xlast = out + (size_t)MM * DD;          // [BB][DD]
  float* out_num   = out_xlast + BB * DD;            // [BB][DD]
  float* out_den   = out_num + BB * DD;              // [BB][DD]

  char* ws = (char*)d_ws;
  unsigned short* xb   = (unsigned short*)ws;                 // 33,554,432 B
  unsigned short* wz   = (unsigned short*)(ws + 33554432);    //  6,291,456 B
  unsigned short* wo   = (unsigned short*)(ws + 39845888);    //  2,097,152 B
  float*          bias = (float*)(ws + 41943040);             //     12,288 B
  unsigned short* rwkv = (unsigned short*)(ws + 41955328);    // 33,554,432 B (no alias with xb)

  prep_all<<<1024 + MM * DD / 4 / 256, 256, 0, stream>>>(
      Wk, Wv, Wr, Wo, tmk, tmv, tmr, last_x, (const float4*)x,
      wz, wo, bias, (ushort4*)xb, (float4*)out_xlast);

  // Fused: kvr GEMM + WKV -> rwkv [16384, 1024], plus num/den state rows
  gemm_kvr<<<dim3(16, 64), 512, 0, stream>>>(
      xb, wz, bias, time_first, time_decay, last_num, last_den,
      rwkv, out_num, out_den);

  // out = rwkv @ wo^T : [16384, 1024]
  gemm_bt128<<<dim3(DD / 128, MM / 128), 256, 0, stream>>>(
      rwkv, wo, out, MM, DD, DD);
}

// Round 4
// 298.826 us; speedup vs baseline: 1.1598x; 1.1598x over previous
//
#include <hip/hip_runtime.h>
#include <cstdint>
#include <cstddef>

// Problem constants
constexpr int DD = 1024;        // D
constexpr int TT = 4096;        // T
constexpr int BB = 4;           // B
constexpr int MM = BB * TT;     // 16384 rows

typedef __bf16 bf16x8 __attribute__((ext_vector_type(8)));
typedef float  f32x4  __attribute__((ext_vector_type(4)));

__device__ __forceinline__ unsigned short f2bf(float f) {
  union { float f; uint32_t u; } c; c.f = f;
  uint32_t r = (c.u + 0x7FFFu + ((c.u >> 16) & 1u)) >> 16;
  return (unsigned short)r;
}

__device__ __forceinline__ float fast_rcp(float x) {
  return __builtin_amdgcn_rcpf(x);
}

// async global->LDS 16B per lane; lds_dst must be wave-uniform (HW adds lane*16)
__device__ __forceinline__ void async_ld16(const unsigned short* g, unsigned short* lds_dst) {
  __builtin_amdgcn_global_load_lds(
      (const __attribute__((address_space(1))) void*)g,
      (__attribute__((address_space(3))) void*)lds_dst,
      16, 0, 0);
}

// ---------------------------------------------------------------------------
// Merged prep: blocks [0,1024) fold time-mix into weights (wave per row) and
// accumulate bias dots; blocks [1024, 1024+16384) convert x to bf16 and emit
// x[:, T-1, :].
__global__ void prep_all(const float* __restrict__ Wk, const float* __restrict__ Wv,
                         const float* __restrict__ Wr, const float* __restrict__ Wo,
                         const float* __restrict__ tmk, const float* __restrict__ tmv,
                         const float* __restrict__ tmr,
                         const float* __restrict__ last_x,
                         const float4* __restrict__ x,
                         unsigned short* __restrict__ wz,   // [3][1024][1024] bf16
                         unsigned short* __restrict__ wo,   // [1024][1024] bf16
                         float* __restrict__ bias,          // [3][1024]
                         ushort4* __restrict__ xb,          // [16384][1024] bf16
                         float4* __restrict__ out_xlast) {
  if (blockIdx.x < 1024) {
    int w = (blockIdx.x * 256 + threadIdx.x) >> 6;   // 0..4095
    int lane = threadIdx.x & 63;
    int z = w >> 10;           // 0..3
    int e = w & (DD - 1);
    const float* W  = (z == 0) ? Wk  : (z == 1) ? Wv  : (z == 2) ? Wr : Wo;
    const float* tm = (z == 0) ? tmk : (z == 1) ? tmv : tmr;
    unsigned short* dst = (z < 3) ? (wz + (size_t)z * DD * DD + (size_t)e * DD)
                                  : (wo + (size_t)e * DD);
    float s = 0.f;
#pragma unroll
    for (int j = 0; j < 4; ++j) {
      int d = j * 256 + lane * 4;
      float4 wv4 = *(const float4*)(W + (size_t)e * DD + d);
      if (z < 3) {
        float4 t4 = *(const float4*)(tm + d);
        float4 l4 = *(const float4*)(last_x + d);
        s += l4.x * (1.f - t4.x) * wv4.x + l4.y * (1.f - t4.y) * wv4.y +
             l4.z * (1.f - t4.z) * wv4.z + l4.w * (1.f - t4.w) * wv4.w;
        wv4.x *= t4.x; wv4.y *= t4.y; wv4.z *= t4.z; wv4.w *= t4.w;
      }
      ushort4 o;
      o.x = f2bf(wv4.x); o.y = f2bf(wv4.y); o.z = f2bf(wv4.z); o.w = f2bf(wv4.w);
      *(ushort4*)(dst + d) = o;
    }
    if (z < 3) {
      for (int off = 32; off; off >>= 1) s += __shfl_down(s, off, 64);
      if (lane == 0) bias[z * DD + e] = s;
    }
  } else {
    int i = (blockIdx.x - 1024) * 256 + threadIdx.x;  // < MM*DD/4
    float4 v = x[i];
    ushort4 o;
    o.x = f2bf(v.x); o.y = f2bf(v.y); o.z = f2bf(v.z); o.w = f2bf(v.w);
    xb[i] = o;
    int m = i >> 8;                                    // 256 float4 per row
    if ((m & (TT - 1)) == (TT - 1)) {
      int b = m >> 12;
      out_xlast[b * 256 + (i & 255)] = v;
    }
  }
}

// ---------------------------------------------------------------------------
// Fused GEMM1 + WKV. R0's verified 2-barrier two-panel BK=64 structure,
// 128m x 64n(x3z) block tile — but with 8 waves of 32x32x3z instead of
// 4 waves of 64x32x3z. acc = 48 AGPR/wave (was 96) -> total regs/wave < 128
// -> 4 waves/SIMD (2 blocks/CU resident) instead of 2. The m114 implicit
// cross-wave overlap then hides the barrier drain that capped R0 at 37% MFMA.
__global__ __launch_bounds__(512, 4) void gemm_kvr(
    const unsigned short* __restrict__ A,     // [16384][1024] bf16
    const unsigned short* __restrict__ Wz,    // [3][1024][1024] bf16
    const float* __restrict__ bias,           // [3][1024]
    const float* __restrict__ time_first, const float* __restrict__ time_decay,
    const float* __restrict__ last_num, const float* __restrict__ last_den,
    unsigned short* __restrict__ rwkv,        // [16384][1024] bf16
    float* __restrict__ out_num, float* __restrict__ out_den) {
  __shared__ unsigned short lA[2][128 * 32];      // [half][row][col] 16 KiB
  __shared__ unsigned short lB[2][3][64 * 32];    // [half][z][row][col] 24 KiB
  const int tid  = threadIdx.x;
  const int lane = tid & 63;
  const int wave = tid >> 6;    // 0..7

  // XCD-aware remap of (n0, m0). Grid: 16 x 128 = 2048 blocks.
  const int id  = blockIdx.y * gridDim.x + blockIdx.x;   // 0..2047
  const int xcd = id & 7;
  const int s   = id >> 3;                               // 0..255
  const int m0 = (xcd * 16 + (s >> 4)) * 128;            // m-stripe
  const int n0 = (s & 15) * 64;                          // zone-local col base

  const int wm = (wave >> 1) * 32;   // 4 m-groups of 32
  const int wn = (wave & 1) * 32;    // 2 n-groups of 32

  f32x4 acc[3][2][2] = {};

  const int fr_row = lane & 15;
  const int fr_kb  = (lane >> 4) * 16;   // byte offset within row (8 bf16)

  // Staging maps (per-lane global addresses; wave-uniform LDS bases).
  // A: 128x32 half = 8 KiB = 512 chunks of 16B; chunk = tid.
  const size_t aOff = (size_t)(m0 + (tid >> 2)) * DD + (tid & 3) * 8;
  // B: 3x64x32 half = 12 KiB = 768 chunks; chunk c = wave*64+lane (+512, waves 0-3).
  const int c1 = wave * 64 + lane;
  const size_t bOff1 = (size_t)(c1 >> 8) * DD * DD +
                       (size_t)(n0 + ((c1 >> 2) & 63)) * DD + (c1 & 3) * 8;
  const int c2 = 512 + wave * 64 + lane;   // z = 2
  const size_t bOff2 = (size_t)2 * DD * DD +
                       (size_t)(n0 + ((c2 >> 2) & 63)) * DD + (c2 & 3) * 8;

  for (int k0 = 0; k0 < DD; k0 += 64) {
    __syncthreads();
#pragma unroll
    for (int h = 0; h < 2; ++h) {
      int kk = k0 + h * 32;
      async_ld16(A + aOff + kk, lA[h] + (size_t)(wave * 64) * 8);
      async_ld16(Wz + bOff1 + kk, (unsigned short*)lB[h] + (size_t)(wave * 64) * 8);
      if (wave < 4)
        async_ld16(Wz + bOff2 + kk, (unsigned short*)lB[h] + (size_t)(512 + wave * 64) * 8);
    }
    __syncthreads();

#pragma unroll
    for (int h = 0; h < 2; ++h) {
      bf16x8 af[2], bfr[3][2];
#pragma unroll
      for (int i = 0; i < 2; ++i)
        af[i] = *(const bf16x8*)((const char*)lA[h] + ((wm + i * 16 + fr_row) * 64 + fr_kb));
#pragma unroll
      for (int z = 0; z < 3; ++z)
#pragma unroll
        for (int j = 0; j < 2; ++j)
          bfr[z][j] = *(const bf16x8*)((const char*)lB[h][z] + ((wn + j * 16 + fr_row) * 64 + fr_kb));

#pragma unroll
      for (int mi = 0; mi < 2; ++mi)
#pragma unroll
        for (int z = 0; z < 3; ++z)
#pragma unroll
          for (int ni = 0; ni < 2; ++ni)
            acc[z][mi][ni] = __builtin_amdgcn_mfma_f32_16x16x32_bf16(
                af[mi], bfr[z][ni], acc[z][mi][ni], 0, 0, 0);
    }
  }

  // Epilogue: WKV in-register. C/D layout: col = lane&15, row = (lane>>4)*4 + reg.
  const int crow = (lane >> 4) * 4;
  const int ccol = lane & 15;
#pragma unroll
  for (int ni = 0; ni < 2; ++ni) {
    int gnz = n0 + wn + ni * 16 + ccol;   // zone-local channel d
    float bk = bias[gnz], bv = bias[DD + gnz], br = bias[2 * DD + gnz];
    float tf = time_first[gnz];
    float ln = last_num[gnz], ld = last_den[gnz];
    float dec = __expf(-__expf(time_decay[gnz]));   // hoisted
#pragma unroll
    for (int mi = 0; mi < 2; ++mi) {
#pragma unroll
      for (int r = 0; r < 4; ++r) {
        int gm = m0 + wm + mi * 16 + crow + r;
        float kk = acc[0][mi][ni][r] + bk;
        float vv = acc[1][mi][ni][r] + bv;
        float rr = acc[2][mi][ni][r] + br;
        float efk = __expf(tf + kk);
        float wkv = (ln + efk * vv) * fast_rcp(ld + efk);
        float sr  = fast_rcp(1.0f + __expf(-rr));
        rwkv[(size_t)gm * DD + gnz] = f2bf(sr * wkv);
        if ((gm & (TT - 1)) == (TT - 1)) {
          int b = gm >> 12;
          float ek = __expf(kk);
          out_num[b * DD + gnz] = dec * ln + ek * vv;
          out_den[b * DD + gnz] = dec * ld + ek;
        }
      }
    }
  }
}

// ---------------------------------------------------------------------------
// GEMM2: C[M,N] = A[M,K] @ B[N,K]^T, fp32 out. Two-panel BK=64 (R3 structure)
// + XCD-locality swizzle.
__global__ void gemm_bt128(const unsigned short* __restrict__ A,
                           const unsigned short* __restrict__ Bw,
                           float* __restrict__ Cf,
                           int M, int N, int K) {
  __shared__ unsigned short lA[2][128 * 32];
  __shared__ unsigned short lB[2][128 * 32];
  const int tid  = threadIdx.x;
  const int lane = tid & 63;
  const int wave = tid >> 6;

  // XCD-aware remap: m-stripes partitioned across XCDs, n fastest.
  const int nBlocks = N >> 7;
  const int mBlocks = M >> 7;
  const int id  = blockIdx.y * gridDim.x + blockIdx.x;
  const int xcd = id & 7;
  const int s   = id >> 3;
  const int mPer = mBlocks >> 3;           // m-stripes per XCD (M=16384 -> 16)
  const int m0 = (xcd * mPer + s / nBlocks) * 128;
  const int n0 = (s % nBlocks) * 128;

  const int wm = (wave >> 1) * 64;
  const int wn = (wave & 1) * 64;

  f32x4 acc[4][4] = {};
  const int fr_row = lane & 15;
  const int fr_kb  = (lane >> 4) * 16;
  const int scol = (tid & 3) * 8;

  for (int k0 = 0; k0 < K; k0 += 64) {
    __syncthreads();
#pragma unroll
    for (int h = 0; h < 2; ++h) {
      int kk = k0 + h * 32;
#pragma unroll
      for (int it = 0; it < 2; ++it) {
        int cc  = it * 256 + tid;
        int row = cc >> 2;
        async_ld16(A + (size_t)(m0 + row) * K + (kk + scol),
                   lA[h] + (size_t)(it * 256 + wave * 64) * 8);
      }
#pragma unroll
      for (int it = 0; it < 2; ++it) {
        int cc  = it * 256 + tid;
        int row = cc >> 2;
        async_ld16(Bw + (size_t)(n0 + row) * K + (kk + scol),
                   lB[h] + (size_t)(it * 256 + wave * 64) * 8);
      }
    }
    __syncthreads();

#pragma unroll
    for (int h = 0; h < 2; ++h) {
      bf16x8 af[4], bfr[4];
#pragma unroll
      for (int i = 0; i < 4; ++i) {
        af[i]  = *(const bf16x8*)((const char*)lA[h] + ((wm + i * 16 + fr_row) * 64 + fr_kb));
        bfr[i] = *(const bf16x8*)((const char*)lB[h] + ((wn + i * 16 + fr_row) * 64 + fr_kb));
      }
#pragma unroll
      for (int mi = 0; mi < 4; ++mi)
#pragma unroll
        for (int ni = 0; ni < 4; ++ni)
          acc[mi][ni] = __builtin_amdgcn_mfma_f32_16x16x32_bf16(af[mi], bfr[ni], acc[mi][ni], 0, 0, 0);
    }
  }

  const int crow = (lane >> 4) * 4;
  const int ccol = lane & 15;
#pragma unroll
  for (int mi = 0; mi < 4; ++mi) {
#pragma unroll
    for (int ni = 0; ni < 4; ++ni) {
      int gn = n0 + wn + ni * 16 + ccol;
#pragma unroll
      for (int r = 0; r < 4; ++r) {
        int gm = m0 + wm + mi * 16 + crow + r;
        Cf[(size_t)gm * N + gn] = acc[mi][ni][r];
      }
    }
  }
}

// ---------------------------------------------------------------------------
extern "C" void kernel_launch(void* const* d_in, const int* in_sizes, int n_in,
                              void* d_out, int out_size, void* d_ws, size_t ws_size,
                              hipStream_t stream) {
  const float* x          = (const float*)d_in[0];
  const float* last_x     = (const float*)d_in[1];
  const float* last_num   = (const float*)d_in[2];
  const float* last_den   = (const float*)d_in[3];
  const float* time_decay = (const float*)d_in[4];
  const float* time_first = (const float*)d_in[5];
  const float* tmk        = (const float*)d_in[6];
  const float* tmv        = (const float*)d_in[7];
  const float* tmr        = (const float*)d_in[8];
  const float* Wk         = (const float*)d_in[9];
  const float* Wv         = (const float*)d_in[10];
  const float* Wr         = (const float*)d_in[11];
  const float* Wo         = (const float*)d_in[12];

  float* out       = (float*)d_out;                  // [MM][DD]
  float* out_xlast = out + (size_t)MM * DD;          // [BB][DD]
  float* out_num   = out_xlast + BB * DD;            // [BB][DD]
  float* out_den   = out_num + BB * DD;              // [BB][DD]

  char* ws = (char*)d_ws;
  unsigned short* xb   = (unsigned short*)ws;                 // 33,554,432 B
  unsigned short* wz   = (unsigned short*)(ws + 33554432);    //  6,291,456 B
  unsigned short* wo   = (unsigned short*)(ws + 39845888);    //  2,097,152 B
  float*          bias = (float*)(ws + 41943040);             //     12,288 B
  unsigned short* rwkv = (unsigned short*)(ws + 41955328);    // 33,554,432 B (no alias with xb)

  prep_all<<<1024 + MM * DD / 4 / 256, 256, 0, stream>>>(
      Wk, Wv, Wr, Wo, tmk, tmv, tmr, last_x, (const float4*)x,
      wz, wo, bias, (ushort4*)xb, (float4*)out_xlast);

  // Fused: kvr GEMM + WKV -> rwkv [16384, 1024], plus num/den state rows
  gemm_kvr<<<dim3(16, 128), 512, 0, stream>>>(
      xb, wz, bias, time_first, time_decay, last_num, last_den,
      rwkv, out_num, out_den);

  // out = rwkv @ wo^T : [16384, 1024]
  gemm_bt128<<<dim3(DD / 128, MM / 128), 256, 0, stream>>>(
      rwkv, wo, out, MM, DD, DD);
}